// Round 13
// baseline (3629.793 us; speedup 1.0000x reference)
//
#include <hip/hip_runtime.h>

#define LSEQ 512
#define BATCH 256
#define KDIM 256
#define STATE 128

using f32x4  = __attribute__((ext_vector_type(4))) float;
using short8 = __attribute__((ext_vector_type(8))) short;
using u32x2  = __attribute__((ext_vector_type(2))) unsigned int;
using u32x4  = __attribute__((ext_vector_type(4))) unsigned int;

__device__ __forceinline__ float bf2f(unsigned short u){
  return __uint_as_float(((unsigned int)u) << 16);
}
__device__ __forceinline__ unsigned short f2bf(float f){
  unsigned int u = __float_as_uint(f);
  u += 0x7FFFu + ((u >> 16) & 1u);   // RNE
  return (unsigned short)(u >> 16);
}
__device__ __forceinline__ float fast_tanh(float x){
  float ax = fabsf(x);
  float e  = __expf(2.0f * ax);
  float t  = 1.0f - 2.0f / (e + 1.0f);
  return copysignf(t, x);
}
__device__ __forceinline__ float fast_sig(float x){
  return 1.0f / (1.0f + __expf(-x));
}
__device__ __forceinline__ f32x4 mfma16(short8 a, short8 b, f32x4 c){
  return __builtin_amdgcn_mfma_f32_16x16x32_bf16(a, b, c, 0, 0, 0);
}

__device__ __forceinline__ int swz128 (int b){ return b ^ ((((b >> 7) & 7) << 4)); }
__device__ __forceinline__ int swz256 (int b){ return b ^ ((((b >> 8) & 7) << 4)); }
__device__ __forceinline__ int swz512 (int b){ return b ^ ((((b >> 9) & 7) << 4)); }

// ---- Infinity-Cache-scope accessors (sc0 sc1): coherent on any XCD placement.
__device__ __forceinline__ void st_b128_ic(void* p, u32x4 v){
  asm volatile("global_store_dwordx4 %0, %1, off sc0 sc1" :: "v"(p), "v"(v) : "memory");
}
__device__ __forceinline__ void st_b64_ic(void* p, u32x2 v){
  asm volatile("global_store_dwordx2 %0, %1, off sc0 sc1" :: "v"(p), "v"(v) : "memory");
}
#define LD2_IC(dst, p) asm volatile("global_load_dwordx2 %0, %1, off sc0 sc1" : "=v"(dst) : "v"(p) : "memory")

__device__ __forceinline__ f32x4 cvt4(u32x2 q){
  f32x4 r;
  r[0] = __uint_as_float(q[0] << 16);
  r[1] = __uint_as_float(q[0] & 0xFFFF0000u);
  r[2] = __uint_as_float(q[1] << 16);
  r[3] = __uint_as_float(q[1] & 0xFFFF0000u);
  return r;
}

// ---------------- weight convert: f32 src[rowoff+k][coloff+n] -> bf16 dst[n*K+k] ----------------
struct WDesc { const float* src; unsigned short* dst; int K, N, ld, rowoff, coloff; };
struct WDescs { WDesc d[24]; };

__global__ __launch_bounds__(256,4) void convert_weights(WDescs ds){
  WDesc w = ds.d[blockIdx.y];
  int total = w.K * w.N;
  int idx = blockIdx.x * 256 + threadIdx.x;
  if (idx < total){
    int n = idx / w.K;
    int k = idx - n * w.K;
    w.dst[idx] = f2bf(w.src[(size_t)(w.rowoff + k) * w.ld + w.coloff + n]);
  }
}

__global__ __launch_bounds__(256,1) void init_flags(int* flags){
  flags[blockIdx.x * 256 + threadIdx.x] = 0;
}

// ---------------- compose: GA[n][k2] = sum_n2 Wa2[k2][n2]*fAp[n][n2];  gb[n] = ba2.fAp[n] + pb[n] ----------------
// Folds a_seq = a1t@Wa2+ba2 into the posterior pre-projection (exact algebra).
__global__ __launch_bounds__(256,4) void compose_GA(
    const float* __restrict__ Wa2, const float* __restrict__ ba2,
    const unsigned short* __restrict__ fAp,   // [1024 n][256 n2] bf16
    const float* __restrict__ pf1b, const float* __restrict__ pf2b,
    unsigned short* __restrict__ GA,          // [1024 n][256 k2] bf16
    float* __restrict__ gb)                   // [1024] f32
{
  const int n = blockIdx.x;
  const int k2 = threadIdx.x;
  const unsigned short* fr = fAp + (size_t)n * 256;
  const float* wr = Wa2 + (size_t)k2 * 256;
  float s = 0.f;
  for (int j = 0; j < 256; j++) s += wr[j] * bf2f(fr[j]);
  GA[(size_t)n * 256 + k2] = f2bf(s);
  if (k2 == 0){
    float b = 0.f;
    for (int j = 0; j < 256; j++) b += ba2[j] * bf2f(fr[j]);
    gb[n] = b + ((n < 512) ? pf1b[n] : pf2b[n - 512]);
  }
}

// ---------------- gemm_multi: reg-staged path (f32 A inputs; K=64 embeddings) ----------------
struct GArg {
  const void* A; const unsigned short* Bt; const float* bias; const float* bias2;
  unsigned short* C; int lda, ldc, coff, K, act, a_f32;
};
struct GArgs { GArg g[4]; };

__global__ __launch_bounds__(256,2) void gemm_multi(GArgs args){
  GArg ga = args.g[blockIdx.z];
  __shared__ __align__(16) unsigned short lsA[128*64];
  __shared__ __align__(16) unsigned short lsB[128*64];
  const int tid  = threadIdx.x;
  const int wave = tid >> 6, lane = tid & 63;
  const int col_l = lane & 15, rgrp = lane >> 4;
  const int m0 = blockIdx.x * 128, n0 = blockIdx.y * 128;
  const int wm = (wave >> 1) * 64, wn = (wave & 1) * 64;

  f32x4 acc[4][4];
  const f32x4 z4 = {0.f,0.f,0.f,0.f};
  #pragma unroll
  for (int i=0;i<4;i++){ acc[i][0]=z4; acc[i][1]=z4; acc[i][2]=z4; acc[i][3]=z4; }

  const int srow = tid >> 1;
  const int sbe  = (tid & 1) * 32;

  for (int k0 = 0; k0 < ga.K; k0 += 64){
    uint4 av[4], bv[4];
    if (ga.a_f32){
      const float* Ap = (const float*)ga.A + (size_t)(m0 + srow) * ga.lda + k0 + sbe;
      uint4 fv[8];
      #pragma unroll
      for (int i=0;i<8;i++) fv[i] = *(const uint4*)((const char*)Ap + i*16);
      #pragma unroll
      for (int i=0;i<4;i++){
        const float* f = (const float*)&fv[i*2];
        uint4 o;
        o.x = (unsigned)f2bf(f[0]) | ((unsigned)f2bf(f[1]) << 16);
        o.y = (unsigned)f2bf(f[2]) | ((unsigned)f2bf(f[3]) << 16);
        o.z = (unsigned)f2bf(f[4]) | ((unsigned)f2bf(f[5]) << 16);
        o.w = (unsigned)f2bf(f[6]) | ((unsigned)f2bf(f[7]) << 16);
        av[i] = o;
      }
    } else {
      const unsigned short* Ap = (const unsigned short*)ga.A + (size_t)(m0 + srow) * ga.lda + k0 + sbe;
      #pragma unroll
      for (int i=0;i<4;i++) av[i] = *(const uint4*)((const char*)Ap + i*16);
    }
    const unsigned short* Bp = ga.Bt + (size_t)(n0 + srow) * ga.K + k0 + sbe;
    #pragma unroll
    for (int i=0;i<4;i++) bv[i] = *(const uint4*)((const char*)Bp + i*16);

    __syncthreads();
    #pragma unroll
    for (int i=0;i<4;i++){
      *(uint4*)((char*)lsA + swz128(srow*128 + sbe*2 + i*16)) = av[i];
      *(uint4*)((char*)lsB + swz128(srow*128 + sbe*2 + i*16)) = bv[i];
    }
    __syncthreads();
    #pragma unroll
    for (int kk=0; kk<2; kk++){
      short8 af[4], bfr[4];
      #pragma unroll
      for (int mt=0; mt<4; mt++)
        af[mt] = *(const short8*)((const char*)lsA + swz128((wm + mt*16 + col_l)*128 + kk*64 + rgrp*16));
      #pragma unroll
      for (int nt=0; nt<4; nt++)
        bfr[nt] = *(const short8*)((const char*)lsB + swz128((wn + nt*16 + col_l)*128 + kk*64 + rgrp*16));
      #pragma unroll
      for (int mt=0; mt<4; mt++)
        #pragma unroll
        for (int nt=0; nt<4; nt++)
          acc[mt][nt] = mfma16(af[mt], bfr[nt], acc[mt][nt]);
    }
  }
  #pragma unroll
  for (int nt=0; nt<4; nt++){
    int col = n0 + wn + nt*16 + col_l;
    const float* bsrc = (col < 512) ? ga.bias : ga.bias2;
    float bb = bsrc ? bsrc[col & 511] : 0.0f;
    #pragma unroll
    for (int mt=0; mt<4; mt++){
      #pragma unroll
      for (int r=0; r<4; r++){
        int row = m0 + wm + mt*16 + rgrp*4 + r;
        float v = acc[mt][nt][r] + bb;
        if (ga.act == 1) v = fast_tanh(v);
        ga.C[(size_t)row * ga.ldc + ga.coff + col] = f2bf(v);
      }
    }
  }
}

// ---------------- gemm_glds: bf16 GEMM with global_load_lds(16B) staging ----------------
struct GArg2 {
  const unsigned short* A; const unsigned short* Bt; const float* bias; const float* bias2;
  unsigned short* C; int lda, ldc, coff, K, act;
};
struct GArgs2 { GArg2 g[2]; };

__global__ __launch_bounds__(256,2) void gemm_glds(GArgs2 args){
  GArg2 ga = args.g[blockIdx.z];
  __shared__ __align__(16) unsigned short ls[4][128*64];  // A0,B0,A1,B1
  const int tid  = threadIdx.x;
  const int wave = tid >> 6, lane = tid & 63;
  const int col_l = lane & 15, rgrp = lane >> 4;
  const int m0 = blockIdx.x * 128, n0 = blockIdx.y * 128;
  const int wm = (wave >> 1) * 64, wn = (wave & 1) * 64;

  const int lrow = lane >> 3;
  const int scol = (((lane & 7) ^ lrow) << 3);

  auto STAGE = [&](int k0, int buf){
    #pragma unroll
    for (int c = 0; c < 4; c++){
      int srow = wave*32 + c*8 + lrow;
      const unsigned short* pa = ga.A  + (size_t)(m0 + srow) * ga.lda + k0 + scol;
      const unsigned short* pb = ga.Bt + (size_t)(n0 + srow) * ga.K  + k0 + scol;
      __builtin_amdgcn_global_load_lds(
          (const __attribute__((address_space(1))) unsigned int*)pa,
          (__attribute__((address_space(3))) unsigned int*)((char*)&ls[buf*2][0]   + wave*4096 + c*1024),
          16, 0, 0);
      __builtin_amdgcn_global_load_lds(
          (const __attribute__((address_space(1))) unsigned int*)pb,
          (__attribute__((address_space(3))) unsigned int*)((char*)&ls[buf*2+1][0] + wave*4096 + c*1024),
          16, 0, 0);
    }
  };

  f32x4 acc[4][4];
  const f32x4 z4 = {0.f,0.f,0.f,0.f};
  #pragma unroll
  for (int i=0;i<4;i++){ acc[i][0]=z4; acc[i][1]=z4; acc[i][2]=z4; acc[i][3]=z4; }

  const int niter = ga.K >> 6;
  STAGE(0, 0);

  for (int i = 0; i < niter; i++){
    if (i + 1 < niter){
      STAGE((i+1)*64, (i+1) & 1);
      asm volatile("s_waitcnt vmcnt(8)" ::: "memory");
    } else {
      asm volatile("s_waitcnt vmcnt(0)" ::: "memory");
    }
    __syncthreads();
    const char* la = (const char*)&ls[(i&1)*2][0];
    const char* lb = (const char*)&ls[(i&1)*2+1][0];
    #pragma unroll
    for (int kk=0; kk<2; kk++){
      short8 af[4], bfr[4];
      #pragma unroll
      for (int mt=0; mt<4; mt++)
        af[mt] = *(const short8*)(la + swz128((wm + mt*16 + col_l)*128 + kk*64 + rgrp*16));
      #pragma unroll
      for (int nt=0; nt<4; nt++)
        bfr[nt] = *(const short8*)(lb + swz128((wn + nt*16 + col_l)*128 + kk*64 + rgrp*16));
      #pragma unroll
      for (int mt=0; mt<4; mt++)
        #pragma unroll
        for (int nt=0; nt<4; nt++)
          acc[mt][nt] = mfma16(af[mt], bfr[nt], acc[mt][nt]);
    }
    __syncthreads();
  }

  #pragma unroll
  for (int nt=0; nt<4; nt++){
    int col = n0 + wn + nt*16 + col_l;
    const float* bsrc = (col < 512) ? ga.bias : ga.bias2;
    float bb = bsrc ? bsrc[col & 511] : 0.0f;
    #pragma unroll
    for (int mt=0; mt<4; mt++){
      #pragma unroll
      for (int r=0; r<4; r++){
        int row = m0 + wm + mt*16 + rgrp*4 + r;
        float v = acc[mt][nt][r] + bb;
        if (ga.act == 1) v = fast_tanh(v);
        ga.C[(size_t)row * ga.ldc + ga.coff + col] = f2bf(v);
      }
    }
  }
}

// ---------------- phase B: tanh-RNN chunk, W_hh held in VGPRs ----------------
__global__ __launch_bounds__(256,1) void rnn_chunk(
    const unsigned short* __restrict__ rnn_in,
    const unsigned short* __restrict__ Whh_t,
    const float* __restrict__ b_hh,
    unsigned short* __restrict__ cat_d,
    float* __restrict__ dn_out,
    unsigned short* __restrict__ d_state,
    int t0, int nsteps)
{
  __shared__ __align__(16) unsigned short dls[16*256];
  const int tid = threadIdx.x, wave = tid >> 6, lane = tid & 63;
  const int col_l = lane & 15, rgrp = lane >> 4;
  const int brow0 = blockIdx.x * 16;
  const int ncol = wave * 64;

  short8 bfr[4][8];
  #pragma unroll
  for (int nt=0; nt<4; nt++){
    const unsigned short* bp = Whh_t + (size_t)(ncol + nt*16 + col_l) * 256;
    #pragma unroll
    for (int kk=0; kk<8; kk++)
      bfr[nt][kk] = *(const short8*)(bp + kk*32 + rgrp*8);
  }
  float bias[4];
  #pragma unroll
  for (int nt=0; nt<4; nt++) bias[nt] = b_hh[ncol + nt*16 + col_l];

  if (t0 == 0){
    for (int i = tid; i < 16*256; i += 256){
      int row = i >> 8, col = i & 255;
      *(unsigned short*)((char*)dls + swz512(row*512 + col*2)) = 0;
    }
  } else {
    const unsigned short* ds = d_state + (size_t)brow0 * 256;
    for (int i = tid; i < 16*256; i += 256){
      int row = i >> 8, col = i & 255;
      *(unsigned short*)((char*)dls + swz512(row*512 + col*2)) = ds[row*256 + col];
    }
  }
  __syncthreads();

  for (int tl=0; tl<nsteps; tl++){
    unsigned short rv[4][4];
    const unsigned short* rp = rnn_in + (size_t)(tl*BATCH + brow0) * 256;
    #pragma unroll
    for (int nt=0; nt<4; nt++)
      #pragma unroll
      for (int r=0; r<4; r++)
        rv[nt][r] = rp[(size_t)(rgrp*4 + r)*256 + ncol + nt*16 + col_l];

    f32x4 acc[4];
    const f32x4 z4 = {0.f,0.f,0.f,0.f};
    acc[0]=z4; acc[1]=z4; acc[2]=z4; acc[3]=z4;
    #pragma unroll
    for (int kk=0; kk<8; kk++){
      short8 af = *(const short8*)((const char*)dls + swz512((lane & 15)*512 + kk*64 + rgrp*16));
      #pragma unroll
      for (int nt=0; nt<4; nt++)
        acc[nt] = mfma16(af, bfr[nt][kk], acc[nt]);
    }
    __syncthreads();
    #pragma unroll
    for (int nt=0; nt<4; nt++){
      #pragma unroll
      for (int r=0; r<4; r++){
        float h = acc[nt][r] + bf2f(rv[nt][r]) + bias[nt];
        float d = fast_tanh(h);
        int row = rgrp*4 + r, col = ncol + nt*16 + col_l;
        unsigned short db = f2bf(d);
        *(unsigned short*)((char*)dls + swz512(row*512 + col*2)) = db;
        cat_d[(size_t)(tl*BATCH + brow0 + row)*512 + col] = db;
        if (t0 + tl == LSEQ-1) dn_out[(size_t)(brow0 + row)*256 + col] = d;
      }
    }
    __syncthreads();
  }
  unsigned short* dso = d_state + (size_t)brow0 * 256;
  for (int i = tid; i < 16*256; i += 256){
    int row = i >> 8, col = i & 255;
    dso[row*256 + col] = *(const unsigned short*)((const char*)dls + swz512(row*512 + col*2));
  }
}

// ---------------- phase D: weight-stationary z recurrence, IC mailbox ----------------
// r6 data path; leaner sync: separate bls bounce (one fewer barrier), per-wave
// flag polling (no post-poll barrier), group flags packed in one 16B line.
__global__ __launch_bounds__(512,1) void zrec_mb(
    const unsigned short* __restrict__ preP, const unsigned short* __restrict__ preQ, // [ns*B,1024]
    const unsigned short* __restrict__ Wzz,  // [4 roles][2 mats][256 n][128 k]
    const unsigned short* __restrict__ W2,   // [4 roles][2 mats][128 n][256 k]
    const float* __restrict__ pmub, const float* __restrict__ plsb, const float* __restrict__ qmub,
    const float* __restrict__ eps,
    float* __restrict__ out_mu, float* __restrict__ out_ls, float* __restrict__ out_zn,
    unsigned short* __restrict__ z_state,
    unsigned short* __restrict__ mb, int* __restrict__ flags,
    int t0, int nsteps, int fbase)
{
  __shared__ __align__(16) unsigned short zls[16*128];
  __shared__ __align__(16) unsigned short tls[16*256];
  __shared__ __align__(16) unsigned short bls[16*256];
  const int tid = threadIdx.x, wave = tid >> 6, lane = tid & 63;
  const int col_l = lane & 15, rgrp = lane >> 4;
  const int bid = blockIdx.x;
  const int c   = (bid >> 3) & 3;
  const int g   = (bid & 7) + ((bid >> 5) << 3);
  const int brow0 = g * 16;
  const int NT2 = (c < 2) ? 2 : 1;

  const unsigned short* pre = (c < 2) ? preP : preQ;
  const int cb = (c & 1) * 256;

  short8 w1[2][2][4];
  {
    const unsigned short* wz = Wzz + (size_t)c * 65536;
    #pragma unroll
    for (int m=0; m<2; m++)
      #pragma unroll
      for (int nt=0; nt<2; nt++){
        int n = wave*32 + nt*16 + col_l;
        #pragma unroll
        for (int kk=0; kk<4; kk++)
          w1[m][nt][kk] = *(const short8*)(wz + (size_t)(m*256 + n)*128 + kk*32 + rgrp*8);
      }
  }
  short8 w2r[2][8];
  {
    const unsigned short* wp = W2 + (size_t)c * 65536;
    #pragma unroll
    for (int nt=0; nt<2; nt++){
      if (nt < NT2){
        int ccol = wave*(16*((c<2)?2:1)) + nt*16;
        int mat = (c < 2) ? (ccol >> 7) : 0;
        int n   = (ccol & 127) + col_l;
        #pragma unroll
        for (int kk=0; kk<8; kk++)
          w2r[nt][kk] = *(const short8*)(wp + (size_t)(mat*128 + n)*256 + kk*32 + rgrp*8);
      }
    }
  }
  // group flags: one 16B line per group (4 ints), 128B stride between groups
  int* const fline  = flags + g*32;
  int* const myflag = fline + c;

  if (t0 == 0){
    for (int i = tid; i < 16*128; i += 512){
      int row = i >> 7, col = i & 127;
      *(unsigned short*)((char*)zls + swz256(row*256 + col*2)) = 0;
    }
  } else {
    const unsigned short* zs = z_state + (size_t)brow0 * 128;
    for (int i = tid; i < 16*128; i += 512){
      int row = i >> 7, col = i & 127;
      *(unsigned short*)((char*)zls + swz256(row*256 + col*2)) = zs[row*128 + col];
    }
  }
  __syncthreads();

  auto LD_PRE = [&](int tl, unsigned short (&pa_)[2][4], unsigned short (&pb_)[2][4]){
    const unsigned short* bA = pre + ((size_t)tl*BATCH + brow0)*1024 + cb;
    #pragma unroll
    for (int nt=0; nt<2; nt++)
      #pragma unroll
      for (int r=0; r<4; r++){
        int row = rgrp*4 + r, col = wave*32 + nt*16 + col_l;
        pa_[nt][r] = bA[(size_t)row*1024 + col];
        pb_[nt][r] = bA[(size_t)row*1024 + 512 + col];
      }
  };

  const int rrow = tid >> 5;
  const int rc0  = (tid & 31) * 4;
  const f32x4 bp4 = *(const f32x4*)(pmub + rc0);
  const f32x4 bl4 = *(const f32x4*)(plsb + rc0);
  const f32x4 bq4 = *(const f32x4*)(qmub + rc0);

  unsigned short pa0[2][4], pb0[2][4], pa1[2][4], pb1[2][4];
  LD_PRE(0, pa0, pb0);

  const f32x4 z4 = {0.f,0.f,0.f,0.f};
  for (int tl=0; tl<nsteps; ++tl){
    size_t growr = (size_t)(t0+tl)*BATCH + brow0 + rrow;
    f32x4 er = *(const f32x4*)(eps + growr*STATE + rc0);
    int nx = (tl+1 < nsteps) ? tl+1 : tl;
    LD_PRE(nx, pa1, pb1);

    // GEMM1: z @ Wf (both mats), K=128
    short8 af1[4];
    #pragma unroll
    for (int kk=0; kk<4; kk++)
      af1[kk] = *(const short8*)((const char*)zls + swz256((lane & 15)*256 + kk*64 + rgrp*16));
    f32x4 a1[2][2];
    a1[0][0]=z4; a1[0][1]=z4; a1[1][0]=z4; a1[1][1]=z4;
    #pragma unroll
    for (int kk=0; kk<4; kk++)
      #pragma unroll
      for (int m=0; m<2; m++)
        #pragma unroll
        for (int nt=0; nt<2; nt++)
          a1[m][nt] = mfma16(af1[kk], w1[m][nt][kk], a1[m][nt]);

    #pragma unroll
    for (int nt=0; nt<2; nt++)
      #pragma unroll
      for (int r=0; r<4; r++){
        float h1 = a1[0][nt][r] + bf2f(pa0[nt][r]);
        float h2 = a1[1][nt][r] + bf2f(pb0[nt][r]);
        float tv = fast_tanh(h1) * fast_sig(h2);
        int row = rgrp*4 + r, tcol = wave*32 + nt*16 + col_l;
        *(unsigned short*)((char*)tls + swz512(row*512 + tcol*2)) = f2bf(tv);
      }
    __syncthreads();                 // (1) t visible

    // GEMM2: t @ Wh (local k-slice), K=256; bounce into separate bls
    f32x4 a2[2];
    a2[0]=z4; a2[1]=z4;
    #pragma unroll
    for (int kk=0; kk<8; kk++){
      short8 af2 = *(const short8*)((const char*)tls + swz512((lane & 15)*512 + kk*64 + rgrp*16));
      #pragma unroll
      for (int nt=0; nt<2; nt++)
        if (nt < NT2) a2[nt] = mfma16(af2, w2r[nt][kk], a2[nt]);
    }
    if (c < 2){
      #pragma unroll
      for (int nt=0; nt<2; nt++)
        #pragma unroll
        for (int r=0; r<4; r++)
          bls[(rgrp*4 + r)*256 + wave*32 + nt*16 + col_l] = f2bf(a2[nt][r]);
    } else {
      #pragma unroll
      for (int r=0; r<4; r++)
        bls[(rgrp*4 + r)*128 + wave*16 + col_l] = f2bf(a2[0][r]);
    }
    __syncthreads();                 // (2) bls visible

    // packed publish: one vector IC store per thread
    unsigned short* slot = mb + (size_t)((g*2 + (tl & 1))*4 + c)*4096;
    if (c < 2){
      u32x4 v = *(const u32x4*)((const char*)bls + tid*16);
      st_b128_ic(slot + tid*8, v);
    } else {
      u32x2 v = *(const u32x2*)((const char*)bls + tid*8);
      st_b64_ic(slot + tid*4, v);
    }
    asm volatile("s_waitcnt vmcnt(0)" ::: "memory");  // this wave's stores complete
    __syncthreads();                 // (3) all waves' stores complete
    const int target = fbase + tl + 1;
    if (tid == 0)
      __hip_atomic_store(myflag, target, __ATOMIC_RELAXED, __HIP_MEMORY_SCOPE_AGENT);

    // per-wave poll: lane 0 of EVERY wave checks all peers in one x4 load
    if (lane == 0){
      u32x4 F;
      for (;;){
        asm volatile("global_load_dwordx4 %0, %1, off sc0 sc1\n\ts_waitcnt vmcnt(0)"
                     : "=v"(F) : "v"(fline) : "memory");
        int ok = 1;
        #pragma unroll
        for (int p=0; p<4; p++)
          if (p != c && (int)F[p] < target) ok = 0;
        if (ok) break;
        __builtin_amdgcn_s_sleep(1);
      }
    }
    // wave proceeds as soon as its lane-0 detects (no block barrier)

    const unsigned short* mbb = mb + (size_t)((g*2 + (tl & 1))*4)*4096;
    const unsigned short* s0 = mbb;
    const unsigned short* s1 = mbb + 4096;
    const unsigned short* s2 = mbb + 8192;
    const unsigned short* s3 = mbb + 12288;
    u32x2 q0,q1,q2,q3,q4,q5;
    LD2_IC(q0, s0 + rrow*256 + rc0);
    LD2_IC(q1, s1 + rrow*256 + rc0);
    LD2_IC(q2, s0 + rrow*256 + 128 + rc0);
    LD2_IC(q3, s1 + rrow*256 + 128 + rc0);
    LD2_IC(q4, s2 + rrow*128 + rc0);
    LD2_IC(q5, s3 + rrow*128 + rc0);
    asm volatile("s_waitcnt vmcnt(0)" ::: "memory");
    __builtin_amdgcn_sched_barrier(0);

    f32x4 mup = cvt4(q0) + cvt4(q1);
    f32x4 lsv = cvt4(q2) + cvt4(q3) + bl4;
    f32x4 muq = cvt4(q4) + cvt4(q5);
    f32x4 muv = (muq + bq4) + (mup + bp4);
    f32x4 zv;
    #pragma unroll
    for (int i=0; i<4; i++) zv[i] = muv[i] + __expf(0.5f * lsv[i]) * er[i];

    unsigned int lo = (unsigned)f2bf(zv[0]) | ((unsigned)f2bf(zv[1]) << 16);
    unsigned int hi = (unsigned)f2bf(zv[2]) | ((unsigned)f2bf(zv[3]) << 16);
    uint2 zp; zp.x = lo; zp.y = hi;
    *(uint2*)((char*)zls + swz256(rrow*256 + rc0*2)) = zp;
    if (c == 0){
      *(f32x4*)(out_mu + growr*STATE + rc0) = muv;
      *(f32x4*)(out_ls + growr*STATE + rc0) = lsv;
      if (t0 + tl == LSEQ-1)
        *(f32x4*)(out_zn + ((size_t)(brow0 + rrow))*STATE + rc0) = zv;
    }
    __syncthreads();                 // (4) z visible; tls/bls reusable

    #pragma unroll
    for (int nt=0; nt<2; nt++)
      #pragma unroll
      for (int r=0; r<4; r++){ pa0[nt][r] = pa1[nt][r]; pb0[nt][r] = pb1[nt][r]; }
  }

  if (c == 0){
    unsigned short* zso = z_state + (size_t)brow0 * 128;
    for (int i = tid; i < 16*128; i += 512){
      int row = i >> 7, col = i & 127;
      zso[row*128 + col] = *(const unsigned short*)((const char*)zls + swz256(row*256 + col*2));
    }
  }
}

// ---------------- host launcher ----------------
extern "C" void kernel_launch(void* const* d_in, const int* in_sizes, int n_in,
                              void* d_out, int out_size, void* d_ws, size_t ws_size,
                              hipStream_t stream)
{
  const float* ext = (const float*)d_in[0];
  const float* obs = (const float*)d_in[1];
  const float* eps = (const float*)d_in[2];
  const float* Wu  = (const float*)d_in[3];
  const float* bu  = (const float*)d_in[4];
  const float* Wx  = (const float*)d_in[5];
  const float* bx  = (const float*)d_in[6];
  const float* W_ih= (const float*)d_in[7];
  const float* b_ih= (const float*)d_in[8];
  const float* W_hh= (const float*)d_in[9];
  const float* b_hh= (const float*)d_in[10];
  const float* Wa1 = (const float*)d_in[11];
  const float* ba1 = (const float*)d_in[12];
  const float* Wa2 = (const float*)d_in[13];
  const float* ba2 = (const float*)d_in[14];
  const float* pf1W= (const float*)d_in[15]; const float* pf1b = (const float*)d_in[16];
  const float* pf2W= (const float*)d_in[17]; const float* pf2b = (const float*)d_in[18];
  const float* pmuW= (const float*)d_in[19]; const float* pmub = (const float*)d_in[20];
  const float* plsW= (const float*)d_in[21]; const float* plsb = (const float*)d_in[22];
  const float* qf1W= (const float*)d_in[23]; const float* qf1b = (const float*)d_in[24];
  const float* qf2W= (const float*)d_in[25]; const float* qf2b = (const float*)d_in[26];
  const float* qmuW= (const float*)d_in[27]; const float* qmub = (const float*)d_in[28];

  int NC = 0;
  const int cands[7] = {1,2,4,8,16,32,64};
  size_t rows = 0;
  for (int ci=0; ci<7; ci++){
    size_t r = (size_t)(LSEQ/cands[ci])*BATCH;
    size_t elems = 3400000 + r*3072;
    if (elems * 2 <= ws_size){ NC = cands[ci]; rows = r; break; }
  }
  if (!NC) return;
  const int nsteps = LSEQ/NC;
  const int gx = (int)(rows/128);

  unsigned short* ws = (unsigned short*)d_ws;
  size_t off = 0;
  auto alloc = [&](size_t elems){
    unsigned short* p = ws + off;
    off += (elems + 127) & ~(size_t)127;
    return p;
  };

  unsigned short* Wu_t  = alloc(64*256);
  unsigned short* Wx_t  = alloc(64*256);
  unsigned short* Wih_t = alloc(256*256);
  unsigned short* Whh_t = alloc(256*256);
  unsigned short* Wa1_t = alloc(512*256);
  unsigned short* Wa2_t = alloc(256*256);
  unsigned short* fAp   = alloc(1024*256);     // [f1(512) | f2(512)] x [256 k]
  unsigned short* fAq   = alloc(1024*256);
  unsigned short* GAp   = alloc(1024*256);     // composite (Wa2 folded) posterior Bt
  float*          gbp   = (float*)alloc(2048); // 1024 f32 composite bias
  unsigned short* Wzz   = alloc(4*2*256*128);
  unsigned short* W2z   = alloc(4*2*128*256);
  unsigned short* d_state = alloc(256*256);
  unsigned short* z_state = alloc(256*128);
  unsigned short* mbx  = alloc(16*2*4*4096);   // bf16 mailbox
  int*   flg  = (int*)alloc(4096);             // 2048 ints (16 groups x 32-int stride)
  unsigned short* bufA  = alloc(rows*256);
  unsigned short* bufB  = alloc(rows*256);
  unsigned short* bufC  = alloc(rows*512);
  unsigned short* preP  = alloc(rows*1024);
  unsigned short* preQ  = alloc(rows*1024);
  if (off * sizeof(unsigned short) > ws_size) return;

  float* out_mu = (float*)d_out;
  float* out_ls = out_mu + (size_t)LSEQ*BATCH*STATE;
  float* out_dn = out_ls + (size_t)LSEQ*BATCH*STATE;
  float* out_zn = out_dn + (size_t)BATCH*KDIM;

  WDescs wd;
  int wi = 0;
  auto add = [&](const float* s, unsigned short* d, int Kk, int Nn, int ld, int ro, int co){
    wd.d[wi].src = s; wd.d[wi].dst = d; wd.d[wi].K = Kk; wd.d[wi].N = Nn;
    wd.d[wi].ld = ld; wd.d[wi].rowoff = ro; wd.d[wi].coloff = co; wi++;
  };
  add(Wu,   Wu_t,  64, 256, 256, 0, 0);
  add(Wx,   Wx_t,  64, 256, 256, 0, 0);
  add(W_ih, Wih_t, 256, 256, 256, 0, 0);
  add(W_hh, Whh_t, 256, 256, 256, 0, 0);
  add(Wa1,  Wa1_t, 512, 256, 256, 0, 0);
  add(Wa2,  Wa2_t, 256, 256, 256, 0, 0);
  add(pf1W, fAp,            256, 512, 512, 128, 0);
  add(pf2W, fAp + 512*256,  256, 512, 512, 128, 0);
  add(qf1W, fAq,            256, 512, 512, 128, 0);
  add(qf2W, fAq + 512*256,  256, 512, 512, 128, 0);
  for (int c=0; c<4; c++){
    const float* s1 = (c < 2) ? pf1W : qf1W;
    const float* s2 = (c < 2) ? pf2W : qf2W;
    add(s1, Wzz + (size_t)(c*2+0)*32768, 128, 256, 512, 0, (c&1)*256);
    add(s2, Wzz + (size_t)(c*2+1)*32768, 128, 256, 512, 0, (c&1)*256);
  }
  add(pmuW, W2z + (size_t)(0*2+0)*32768, 256, 128, 128, 0,   0);
  add(plsW, W2z + (size_t)(0*2+1)*32768, 256, 128, 128, 0,   0);
  add(pmuW, W2z + (size_t)(1*2+0)*32768, 256, 128, 128, 256, 0);
  add(plsW, W2z + (size_t)(1*2+1)*32768, 256, 128, 128, 256, 0);
  add(qmuW, W2z + (size_t)(2*2+0)*32768, 256, 128, 128, 0,   0);
  add(qmuW, W2z + (size_t)(3*2+0)*32768, 256, 128, 128, 256, 0);

  convert_weights<<<dim3(512,24), 256, 0, stream>>>(wd);
  compose_GA<<<1024, 256, 0, stream>>>(Wa2, ba2, fAp, pf1b, pf2b, GAp, gbp);
  init_flags<<<8, 256, 0, stream>>>(flg);

  for (int c=0; c<NC; ++c){
    const int t0 = c * nsteps;
    const size_t row0 = (size_t)t0 * BATCH;

    GArgs e{};
    e.g[0] = GArg{ext + row0*64, Wu_t, bu, bu, bufA, 64, 256, 0,   64, 1, 1};
    e.g[1] = GArg{obs + row0*64, Wx_t, bx, bx, bufC, 64, 512, 256, 64, 1, 1};
    gemm_multi<<<dim3(gx,2,2), 256, 0, stream>>>(e);

    GArgs2 rn{};
    rn.g[0] = GArg2{bufA, Wih_t, b_ih, b_ih, bufB, 256, 256, 0, 256, 0};
    gemm_glds<<<dim3(gx,2,1), 256, 0, stream>>>(rn);

    rnn_chunk<<<16, 256, 0, stream>>>(bufB, Whh_t, b_hh, bufC, out_dn, d_state, t0, nsteps);

    GArgs2 a1{};
    a1.g[0] = GArg2{bufC, Wa1_t, ba1, ba1, bufA, 512, 256, 0, 512, 1};
    gemm_glds<<<dim3(gx,2,1), 256, 0, stream>>>(a1);

    // a2 folded into pr.g[0] via compose_GA (GAp/gbp); bufA holds a1t
    GArgs2 pr{};
    pr.g[0] = GArg2{bufA, GAp, gbp, gbp + 512, preP, 256, 1024, 0, 256, 0};
    pr.g[1] = GArg2{bufC, fAq, qf1b, qf2b, preQ, 512, 1024, 0, 256, 0};
    gemm_glds<<<dim3(gx,8,2), 256, 0, stream>>>(pr);

    zrec_mb<<<64, 512, 0, stream>>>(preP, preQ, Wzz, W2z,
                                    pmub, plsb, qmub, eps, out_mu, out_ls, out_zn,
                                    z_state, mbx, flg, t0, nsteps, c*nsteps);
  }
}

// Round 14
// 3517.000 us; speedup vs baseline: 1.0321x; 1.0321x over previous
//
#include <hip/hip_runtime.h>

#define LSEQ 512
#define BATCH 256
#define KDIM 256
#define STATE 128

using f32x4  = __attribute__((ext_vector_type(4))) float;
using short8 = __attribute__((ext_vector_type(8))) short;
using u32x2  = __attribute__((ext_vector_type(2))) unsigned int;
using u32x4  = __attribute__((ext_vector_type(4))) unsigned int;

__device__ __forceinline__ float bf2f(unsigned short u){
  return __uint_as_float(((unsigned int)u) << 16);
}
__device__ __forceinline__ unsigned short f2bf(float f){
  unsigned int u = __float_as_uint(f);
  u += 0x7FFFu + ((u >> 16) & 1u);   // RNE
  return (unsigned short)(u >> 16);
}
__device__ __forceinline__ float fast_tanh(float x){
  float ax = fabsf(x);
  float e  = __expf(2.0f * ax);
  float t  = 1.0f - 2.0f / (e + 1.0f);
  return copysignf(t, x);
}
__device__ __forceinline__ float fast_sig(float x){
  return 1.0f / (1.0f + __expf(-x));
}
__device__ __forceinline__ f32x4 mfma16(short8 a, short8 b, f32x4 c){
  return __builtin_amdgcn_mfma_f32_16x16x32_bf16(a, b, c, 0, 0, 0);
}

__device__ __forceinline__ int swz128 (int b){ return b ^ ((((b >> 7) & 7) << 4)); }
__device__ __forceinline__ int swz256 (int b){ return b ^ ((((b >> 8) & 7) << 4)); }
__device__ __forceinline__ int swz512 (int b){ return b ^ ((((b >> 9) & 7) << 4)); }

__device__ __forceinline__ void st_b128_ic(void* p, u32x4 v){
  asm volatile("global_store_dwordx4 %0, %1, off sc0 sc1" :: "v"(p), "v"(v) : "memory");
}
__device__ __forceinline__ void st_b64_ic(void* p, u32x2 v){
  asm volatile("global_store_dwordx2 %0, %1, off sc0 sc1" :: "v"(p), "v"(v) : "memory");
}
#define LD2_IC(dst, p) asm volatile("global_load_dwordx2 %0, %1, off sc0 sc1" : "=v"(dst) : "v"(p) : "memory")

__device__ __forceinline__ f32x4 cvt4(u32x2 q){
  f32x4 r;
  r[0] = __uint_as_float(q[0] << 16);
  r[1] = __uint_as_float(q[0] & 0xFFFF0000u);
  r[2] = __uint_as_float(q[1] << 16);
  r[3] = __uint_as_float(q[1] & 0xFFFF0000u);
  return r;
}

// ---------------- weight convert ----------------
struct WDesc { const float* src; unsigned short* dst; int K, N, ld, rowoff, coloff; };
struct WDescs { WDesc d[24]; };

__global__ __launch_bounds__(256,4) void convert_weights(WDescs ds){
  WDesc w = ds.d[blockIdx.y];
  int total = w.K * w.N;
  int idx = blockIdx.x * 256 + threadIdx.x;
  if (idx < total){
    int n = idx / w.K;
    int k = idx - n * w.K;
    w.dst[idx] = f2bf(w.src[(size_t)(w.rowoff + k) * w.ld + w.coloff + n]);
  }
}

__global__ __launch_bounds__(256,1) void init_flags(int* flags){
  flags[blockIdx.x * 256 + threadIdx.x] = 0;
}

// ---------------- compose: fold a2 into posterior projection (exact algebra) ----------------
__global__ __launch_bounds__(256,4) void compose_GA(
    const float* __restrict__ Wa2, const float* __restrict__ ba2,
    const unsigned short* __restrict__ fAp,
    const float* __restrict__ pf1b, const float* __restrict__ pf2b,
    unsigned short* __restrict__ GA, float* __restrict__ gb)
{
  const int n = blockIdx.x;
  const int k2 = threadIdx.x;
  const unsigned short* fr = fAp + (size_t)n * 256;
  const float* wr = Wa2 + (size_t)k2 * 256;
  float s = 0.f;
  for (int j = 0; j < 256; j++) s += wr[j] * bf2f(fr[j]);
  GA[(size_t)n * 256 + k2] = f2bf(s);
  if (k2 == 0){
    float b = 0.f;
    for (int j = 0; j < 256; j++) b += ba2[j] * bf2f(fr[j]);
    gb[n] = b + ((n < 512) ? pf1b[n] : pf2b[n - 512]);
  }
}

// ---------------- arg structs ----------------
struct GArg {
  const void* A; const unsigned short* Bt; const float* bias; const float* bias2;
  unsigned short* C; int lda, ldc, coff, K, act, a_f32;
};
struct GArg2 {
  const unsigned short* A; const unsigned short* Bt; const float* bias; const float* bias2;
  unsigned short* C; int lda, ldc, coff, K, act;
};

// ---------------- gemm_multi body (256 logical threads; lsraw >= 32KB) ----------------
__device__ void gemm_multi_body(const GArg ga, int bx, int by, int tid, char* lsraw){
  char* lsA = lsraw;
  char* lsB = lsraw + 16384;
  const int wave = tid >> 6, lane = tid & 63;
  const int col_l = lane & 15, rgrp = lane >> 4;
  const int m0 = bx * 128, n0 = by * 128;
  const int wm = (wave >> 1) * 64, wn = (wave & 1) * 64;

  f32x4 acc[4][4];
  const f32x4 z4 = {0.f,0.f,0.f,0.f};
  #pragma unroll
  for (int i=0;i<4;i++){ acc[i][0]=z4; acc[i][1]=z4; acc[i][2]=z4; acc[i][3]=z4; }

  const int srow = tid >> 1;
  const int sbe  = (tid & 1) * 32;

  for (int k0 = 0; k0 < ga.K; k0 += 64){
    uint4 av[4], bv[4];
    if (ga.a_f32){
      const float* Ap = (const float*)ga.A + (size_t)(m0 + srow) * ga.lda + k0 + sbe;
      uint4 fv[8];
      #pragma unroll
      for (int i=0;i<8;i++) fv[i] = *(const uint4*)((const char*)Ap + i*16);
      #pragma unroll
      for (int i=0;i<4;i++){
        const float* f = (const float*)&fv[i*2];
        uint4 o;
        o.x = (unsigned)f2bf(f[0]) | ((unsigned)f2bf(f[1]) << 16);
        o.y = (unsigned)f2bf(f[2]) | ((unsigned)f2bf(f[3]) << 16);
        o.z = (unsigned)f2bf(f[4]) | ((unsigned)f2bf(f[5]) << 16);
        o.w = (unsigned)f2bf(f[6]) | ((unsigned)f2bf(f[7]) << 16);
        av[i] = o;
      }
    } else {
      const unsigned short* Ap = (const unsigned short*)ga.A + (size_t)(m0 + srow) * ga.lda + k0 + sbe;
      #pragma unroll
      for (int i=0;i<4;i++) av[i] = *(const uint4*)((const char*)Ap + i*16);
    }
    const unsigned short* Bp = ga.Bt + (size_t)(n0 + srow) * ga.K + k0 + sbe;
    #pragma unroll
    for (int i=0;i<4;i++) bv[i] = *(const uint4*)((const char*)Bp + i*16);

    __syncthreads();
    #pragma unroll
    for (int i=0;i<4;i++){
      *(uint4*)(lsA + swz128(srow*128 + sbe*2 + i*16)) = av[i];
      *(uint4*)(lsB + swz128(srow*128 + sbe*2 + i*16)) = bv[i];
    }
    __syncthreads();
    #pragma unroll
    for (int kk=0; kk<2; kk++){
      short8 af[4], bfr[4];
      #pragma unroll
      for (int mt=0; mt<4; mt++)
        af[mt] = *(const short8*)(lsA + swz128((wm + mt*16 + col_l)*128 + kk*64 + rgrp*16));
      #pragma unroll
      for (int nt=0; nt<4; nt++)
        bfr[nt] = *(const short8*)(lsB + swz128((wn + nt*16 + col_l)*128 + kk*64 + rgrp*16));
      #pragma unroll
      for (int mt=0; mt<4; mt++)
        #pragma unroll
        for (int nt=0; nt<4; nt++)
          acc[mt][nt] = mfma16(af[mt], bfr[nt], acc[mt][nt]);
    }
  }
  #pragma unroll
  for (int nt=0; nt<4; nt++){
    int col = n0 + wn + nt*16 + col_l;
    const float* bsrc = (col < 512) ? ga.bias : ga.bias2;
    float bb = bsrc ? bsrc[col & 511] : 0.0f;
    #pragma unroll
    for (int mt=0; mt<4; mt++){
      #pragma unroll
      for (int r=0; r<4; r++){
        int row = m0 + wm + mt*16 + rgrp*4 + r;
        float v = acc[mt][nt][r] + bb;
        if (ga.act == 1) v = fast_tanh(v);
        ga.C[(size_t)row * ga.ldc + ga.coff + col] = f2bf(v);
      }
    }
  }
}

// ---------------- gemm_glds body (256 logical threads; lsraw = 64KB) ----------------
__device__ void gemm_glds_body(const GArg2 ga, int bx, int by, int tid, char* lsraw){
  const int wave = tid >> 6, lane = tid & 63;
  const int col_l = lane & 15, rgrp = lane >> 4;
  const int m0 = bx * 128, n0 = by * 128;
  const int wm = (wave >> 1) * 64, wn = (wave & 1) * 64;

  const int lrow = lane >> 3;
  const int scol = (((lane & 7) ^ lrow) << 3);

  auto STAGE = [&](int k0, int buf){
    #pragma unroll
    for (int c = 0; c < 4; c++){
      int srow = wave*32 + c*8 + lrow;
      const unsigned short* pa = ga.A  + (size_t)(m0 + srow) * ga.lda + k0 + scol;
      const unsigned short* pb = ga.Bt + (size_t)(n0 + srow) * ga.K  + k0 + scol;
      __builtin_amdgcn_global_load_lds(
          (const __attribute__((address_space(1))) unsigned int*)pa,
          (__attribute__((address_space(3))) unsigned int*)(lsraw + buf*32768 + wave*4096 + c*1024),
          16, 0, 0);
      __builtin_amdgcn_global_load_lds(
          (const __attribute__((address_space(1))) unsigned int*)pb,
          (__attribute__((address_space(3))) unsigned int*)(lsraw + buf*32768 + 16384 + wave*4096 + c*1024),
          16, 0, 0);
    }
  };

  f32x4 acc[4][4];
  const f32x4 z4 = {0.f,0.f,0.f,0.f};
  #pragma unroll
  for (int i=0;i<4;i++){ acc[i][0]=z4; acc[i][1]=z4; acc[i][2]=z4; acc[i][3]=z4; }

  const int niter = ga.K >> 6;
  STAGE(0, 0);

  for (int i = 0; i < niter; i++){
    if (i + 1 < niter){
      STAGE((i+1)*64, (i+1) & 1);
      asm volatile("s_waitcnt vmcnt(8)" ::: "memory");
    } else {
      asm volatile("s_waitcnt vmcnt(0)" ::: "memory");
    }
    __syncthreads();
    const char* la = lsraw + (i&1)*32768;
    const char* lb = la + 16384;
    #pragma unroll
    for (int kk=0; kk<2; kk++){
      short8 af[4], bfr[4];
      #pragma unroll
      for (int mt=0; mt<4; mt++)
        af[mt] = *(const short8*)(la + swz128((wm + mt*16 + col_l)*128 + kk*64 + rgrp*16));
      #pragma unroll
      for (int nt=0; nt<4; nt++)
        bfr[nt] = *(const short8*)(lb + swz128((wn + nt*16 + col_l)*128 + kk*64 + rgrp*16));
      #pragma unroll
      for (int mt=0; mt<4; mt++)
        #pragma unroll
        for (int nt=0; nt<4; nt++)
          acc[mt][nt] = mfma16(af[mt], bfr[nt], acc[mt][nt]);
    }
    __syncthreads();
  }

  #pragma unroll
  for (int nt=0; nt<4; nt++){
    int col = n0 + wn + nt*16 + col_l;
    const float* bsrc = (col < 512) ? ga.bias : ga.bias2;
    float bb = bsrc ? bsrc[col & 511] : 0.0f;
    #pragma unroll
    for (int mt=0; mt<4; mt++){
      #pragma unroll
      for (int r=0; r<4; r++){
        int row = m0 + wm + mt*16 + rgrp*4 + r;
        float v = acc[mt][nt][r] + bb;
        if (ga.act == 1) v = fast_tanh(v);
        ga.C[(size_t)row * ga.ldc + ga.coff + col] = f2bf(v);
      }
    }
  }
}

// ---------------- rnn body (256 logical threads; lsraw >= 8KB) ----------------
__device__ void rnn_body(
    const unsigned short* rnn_in, const unsigned short* Whh_t, const float* b_hh,
    unsigned short* cat_d, float* dn_out, unsigned short* d_state,
    int t0, int nsteps, int bx, int tid, char* lsraw)
{
  char* dls = lsraw;   // 16 x 512B
  const int wave = tid >> 6, lane = tid & 63;
  const int col_l = lane & 15, rgrp = lane >> 4;
  const int brow0 = bx * 16;
  const int ncol = wave * 64;

  short8 bfr[4][8];
  #pragma unroll
  for (int nt=0; nt<4; nt++){
    const unsigned short* bp = Whh_t + (size_t)(ncol + nt*16 + col_l) * 256;
    #pragma unroll
    for (int kk=0; kk<8; kk++)
      bfr[nt][kk] = *(const short8*)(bp + kk*32 + rgrp*8);
  }
  float bias[4];
  #pragma unroll
  for (int nt=0; nt<4; nt++) bias[nt] = b_hh[ncol + nt*16 + col_l];

  if (t0 == 0){
    for (int i = tid; i < 16*256; i += 256){
      int row = i >> 8, col = i & 255;
      *(unsigned short*)(dls + swz512(row*512 + col*2)) = 0;
    }
  } else {
    const unsigned short* ds = d_state + (size_t)brow0 * 256;
    for (int i = tid; i < 16*256; i += 256){
      int row = i >> 8, col = i & 255;
      *(unsigned short*)(dls + swz512(row*512 + col*2)) = ds[row*256 + col];
    }
  }
  __syncthreads();

  for (int tl=0; tl<nsteps; tl++){
    unsigned short rv[4][4];
    const unsigned short* rp = rnn_in + (size_t)(tl*BATCH + brow0) * 256;
    #pragma unroll
    for (int nt=0; nt<4; nt++)
      #pragma unroll
      for (int r=0; r<4; r++)
        rv[nt][r] = rp[(size_t)(rgrp*4 + r)*256 + ncol + nt*16 + col_l];

    f32x4 acc[4];
    const f32x4 z4 = {0.f,0.f,0.f,0.f};
    acc[0]=z4; acc[1]=z4; acc[2]=z4; acc[3]=z4;
    #pragma unroll
    for (int kk=0; kk<8; kk++){
      short8 af = *(const short8*)(dls + swz512((lane & 15)*512 + kk*64 + rgrp*16));
      #pragma unroll
      for (int nt=0; nt<4; nt++)
        acc[nt] = mfma16(af, bfr[nt][kk], acc[nt]);
    }
    __syncthreads();
    #pragma unroll
    for (int nt=0; nt<4; nt++){
      #pragma unroll
      for (int r=0; r<4; r++){
        float h = acc[nt][r] + bf2f(rv[nt][r]) + bias[nt];
        float d = fast_tanh(h);
        int row = rgrp*4 + r, col = ncol + nt*16 + col_l;
        unsigned short db = f2bf(d);
        *(unsigned short*)(dls + swz512(row*512 + col*2)) = db;
        cat_d[(size_t)(tl*BATCH + brow0 + row)*512 + col] = db;
        if (t0 + tl == LSEQ-1) dn_out[(size_t)(brow0 + row)*256 + col] = d;
      }
    }
    __syncthreads();
  }
  unsigned short* dso = d_state + (size_t)brow0 * 256;
  for (int i = tid; i < 16*256; i += 256){
    int row = i >> 8, col = i & 255;
    dso[row*256 + col] = *(const unsigned short*)(dls + swz512(row*512 + col*2));
  }
}

// ---------------- zrec body (512 threads; segment [t0, t0+nsteps), poff = offset into chunk pre buffers) ----------------
__device__ void zrec_body(
    const unsigned short* preP, const unsigned short* preQ,
    const unsigned short* Wzz, const unsigned short* W2,
    const float* pmub, const float* plsb, const float* qmub,
    const float* eps, float* out_mu, float* out_ls, float* out_zn,
    unsigned short* z_state, unsigned short* mb, int* flags,
    int t0, int nsteps, int poff, int bid, int tid, char* lsraw)
{
  unsigned short* zls = (unsigned short*)lsraw;            // 4KB
  unsigned short* tls = (unsigned short*)(lsraw + 4096);   // 8KB
  unsigned short* bls = (unsigned short*)(lsraw + 12288);  // 8KB
  const int wave = tid >> 6, lane = tid & 63;
  const int col_l = lane & 15, rgrp = lane >> 4;
  const int c   = (bid >> 3) & 3;
  const int g   = (bid & 7) + ((bid >> 5) << 3);
  const int brow0 = g * 16;
  const int NT2 = (c < 2) ? 2 : 1;

  const unsigned short* pre = (c < 2) ? preP : preQ;
  const int cb = (c & 1) * 256;

  short8 w1[2][2][4];
  {
    const unsigned short* wz = Wzz + (size_t)c * 65536;
    #pragma unroll
    for (int m=0; m<2; m++)
      #pragma unroll
      for (int nt=0; nt<2; nt++){
        int n = wave*32 + nt*16 + col_l;
        #pragma unroll
        for (int kk=0; kk<4; kk++)
          w1[m][nt][kk] = *(const short8*)(wz + (size_t)(m*256 + n)*128 + kk*32 + rgrp*8);
      }
  }
  short8 w2r[2][8];
  {
    const unsigned short* wp = W2 + (size_t)c * 65536;
    #pragma unroll
    for (int nt=0; nt<2; nt++){
      if (nt < NT2){
        int ccol = wave*(16*((c<2)?2:1)) + nt*16;
        int mat = (c < 2) ? (ccol >> 7) : 0;
        int n   = (ccol & 127) + col_l;
        #pragma unroll
        for (int kk=0; kk<8; kk++)
          w2r[nt][kk] = *(const short8*)(wp + (size_t)(mat*128 + n)*256 + kk*32 + rgrp*8);
      }
    }
  }
  int* const fline  = flags + g*32;
  int* const myflag = fline + c;

  if (t0 == 0){
    for (int i = tid; i < 16*128; i += 512){
      int row = i >> 7, col = i & 127;
      *(unsigned short*)((char*)zls + swz256(row*256 + col*2)) = 0;
    }
  } else {
    const unsigned short* zs = z_state + (size_t)brow0 * 128;
    for (int i = tid; i < 16*128; i += 512){
      int row = i >> 7, col = i & 127;
      *(unsigned short*)((char*)zls + swz256(row*256 + col*2)) = zs[row*128 + col];
    }
  }
  __syncthreads();

  auto LD_PRE = [&](int tl, unsigned short (&pa_)[2][4], unsigned short (&pb_)[2][4]){
    const unsigned short* bA = pre + ((size_t)(poff + tl)*BATCH + brow0)*1024 + cb;
    #pragma unroll
    for (int nt=0; nt<2; nt++)
      #pragma unroll
      for (int r=0; r<4; r++){
        int row = rgrp*4 + r, col = wave*32 + nt*16 + col_l;
        pa_[nt][r] = bA[(size_t)row*1024 + col];
        pb_[nt][r] = bA[(size_t)row*1024 + 512 + col];
      }
  };

  const int rrow = tid >> 5;
  const int rc0  = (tid & 31) * 4;
  const f32x4 bp4 = *(const f32x4*)(pmub + rc0);
  const f32x4 bl4 = *(const f32x4*)(plsb + rc0);
  const f32x4 bq4 = *(const f32x4*)(qmub + rc0);

  unsigned short pa0[2][4], pb0[2][4], pa1[2][4], pb1[2][4];
  LD_PRE(0, pa0, pb0);

  const f32x4 z4 = {0.f,0.f,0.f,0.f};
  for (int tl=0; tl<nsteps; ++tl){
    size_t growr = (size_t)(t0+tl)*BATCH + brow0 + rrow;
    f32x4 er = *(const f32x4*)(eps + growr*STATE + rc0);
    int nx = (tl+1 < nsteps) ? tl+1 : tl;
    LD_PRE(nx, pa1, pb1);
    const int par = (t0 + tl) & 1;

    short8 af1[4];
    #pragma unroll
    for (int kk=0; kk<4; kk++)
      af1[kk] = *(const short8*)((const char*)zls + swz256((lane & 15)*256 + kk*64 + rgrp*16));
    f32x4 a1[2][2];
    a1[0][0]=z4; a1[0][1]=z4; a1[1][0]=z4; a1[1][1]=z4;
    #pragma unroll
    for (int kk=0; kk<4; kk++)
      #pragma unroll
      for (int m=0; m<2; m++)
        #pragma unroll
        for (int nt=0; nt<2; nt++)
          a1[m][nt] = mfma16(af1[kk], w1[m][nt][kk], a1[m][nt]);

    #pragma unroll
    for (int nt=0; nt<2; nt++)
      #pragma unroll
      for (int r=0; r<4; r++){
        float h1 = a1[0][nt][r] + bf2f(pa0[nt][r]);
        float h2 = a1[1][nt][r] + bf2f(pb0[nt][r]);
        float tv = fast_tanh(h1) * fast_sig(h2);
        int row = rgrp*4 + r, tcol = wave*32 + nt*16 + col_l;
        *(unsigned short*)((char*)tls + swz512(row*512 + tcol*2)) = f2bf(tv);
      }
    __syncthreads();

    f32x4 a2[2];
    a2[0]=z4; a2[1]=z4;
    #pragma unroll
    for (int kk=0; kk<8; kk++){
      short8 af2 = *(const short8*)((const char*)tls + swz512((lane & 15)*512 + kk*64 + rgrp*16));
      #pragma unroll
      for (int nt=0; nt<2; nt++)
        if (nt < NT2) a2[nt] = mfma16(af2, w2r[nt][kk], a2[nt]);
    }
    if (c < 2){
      #pragma unroll
      for (int nt=0; nt<2; nt++)
        #pragma unroll
        for (int r=0; r<4; r++)
          bls[(rgrp*4 + r)*256 + wave*32 + nt*16 + col_l] = f2bf(a2[nt][r]);
    } else {
      #pragma unroll
      for (int r=0; r<4; r++)
        bls[(rgrp*4 + r)*128 + wave*16 + col_l] = f2bf(a2[0][r]);
    }
    __syncthreads();

    unsigned short* slot = mb + (size_t)((g*2 + par)*4 + c)*4096;
    if (c < 2){
      u32x4 v = *(const u32x4*)((const char*)bls + tid*16);
      st_b128_ic(slot + tid*8, v);
    } else {
      u32x2 v = *(const u32x2*)((const char*)bls + tid*8);
      st_b64_ic(slot + tid*4, v);
    }
    asm volatile("s_waitcnt vmcnt(0)" ::: "memory");
    __syncthreads();
    const int target = t0 + tl + 1;
    if (tid == 0)
      __hip_atomic_store(myflag, target, __ATOMIC_RELAXED, __HIP_MEMORY_SCOPE_AGENT);

    if (lane == 0){
      u32x4 F;
      for (;;){
        asm volatile("global_load_dwordx4 %0, %1, off sc0 sc1\n\ts_waitcnt vmcnt(0)"
                     : "=v"(F) : "v"(fline) : "memory");
        int ok = 1;
        #pragma unroll
        for (int p=0; p<4; p++)
          if (p != c && (int)F[p] < target) ok = 0;
        if (ok) break;
        __builtin_amdgcn_s_sleep(1);
      }
    }

    const unsigned short* mbb = mb + (size_t)((g*2 + par)*4)*4096;
    const unsigned short* s0 = mbb;
    const unsigned short* s1 = mbb + 4096;
    const unsigned short* s2 = mbb + 8192;
    const unsigned short* s3 = mbb + 12288;
    u32x2 q0,q1,q2,q3,q4,q5;
    LD2_IC(q0, s0 + rrow*256 + rc0);
    LD2_IC(q1, s1 + rrow*256 + rc0);
    LD2_IC(q2, s0 + rrow*256 + 128 + rc0);
    LD2_IC(q3, s1 + rrow*256 + 128 + rc0);
    LD2_IC(q4, s2 + rrow*128 + rc0);
    LD2_IC(q5, s3 + rrow*128 + rc0);
    asm volatile("s_waitcnt vmcnt(0)" ::: "memory");
    __builtin_amdgcn_sched_barrier(0);

    f32x4 mup = cvt4(q0) + cvt4(q1);
    f32x4 lsv = cvt4(q2) + cvt4(q3) + bl4;
    f32x4 muq = cvt4(q4) + cvt4(q5);
    f32x4 muv = (muq + bq4) + (mup + bp4);
    f32x4 zv;
    #pragma unroll
    for (int i=0; i<4; i++) zv[i] = muv[i] + __expf(0.5f * lsv[i]) * er[i];

    unsigned int lo = (unsigned)f2bf(zv[0]) | ((unsigned)f2bf(zv[1]) << 16);
    unsigned int hi = (unsigned)f2bf(zv[2]) | ((unsigned)f2bf(zv[3]) << 16);
    uint2 zp; zp.x = lo; zp.y = hi;
    *(uint2*)((char*)zls + swz256(rrow*256 + rc0*2)) = zp;
    if (c == 0){
      *(f32x4*)(out_mu + growr*STATE + rc0) = muv;
      *(f32x4*)(out_ls + growr*STATE + rc0) = lsv;
      if (t0 + tl == LSEQ-1)
        *(f32x4*)(out_zn + ((size_t)(brow0 + rrow))*STATE + rc0) = zv;
    }
    __syncthreads();

    #pragma unroll
    for (int nt=0; nt<2; nt++)
      #pragma unroll
      for (int r=0; r<4; r++){ pa0[nt][r] = pa1[nt][r]; pb0[nt][r] = pb1[nt][r]; }
  }

  if (c == 0){
    unsigned short* zso = z_state + (size_t)brow0 * 128;
    for (int i = tid; i < 16*128; i += 512){
      int row = i >> 7, col = i & 127;
      zso[row*128 + col] = *(const unsigned short*)((const char*)zls + swz256(row*256 + col*2));
    }
  }
}

// ---------------- mega: blocks 0-63 zrec segment; rest = 2 logical prelude blocks each ----------------
struct MegaArgs {
  const unsigned short *zP, *zQ, *Wzz, *W2;
  const float *pmub, *plsb, *qmub, *eps;
  float *out_mu, *out_ls, *out_zn;
  unsigned short *zst, *mb; int *flags;
  int t0z, nsz, poff;
  int stage, gx;
  GArg  e0, e1;
  GArg2 p0, p1;
  const unsigned short *rnn_in, *Whh; const float* b_hh;
  unsigned short* cat_d; float* dn_out; unsigned short* dstt; int t0r, nsr;
};

__global__ __launch_bounds__(512,1) void mega(MegaArgs A){
  __shared__ __align__(16) char smem[131072];
  const int tid = threadIdx.x;
  if ((int)blockIdx.x < 64){
    if (A.nsz > 0)
      zrec_body(A.zP, A.zQ, A.Wzz, A.W2, A.pmub, A.plsb, A.qmub, A.eps,
                A.out_mu, A.out_ls, A.out_zn, A.zst, A.mb, A.flags,
                A.t0z, A.nsz, A.poff, (int)blockIdx.x, tid, smem);
    return;
  }
  const int pb = (int)blockIdx.x - 64;
  const int half = tid >> 8, ltid = tid & 255;
  char* ls = smem + half*65536;
  const int lg = pb*2 + half;
  if (A.stage == 0){
    int bxx = lg % A.gx, t = lg / A.gx;
    gemm_multi_body((t >= 2) ? A.e1 : A.e0, bxx, t & 1, ltid, ls);
  } else if (A.stage == 1 || A.stage == 3){
    int bxx = lg % A.gx, by = lg / A.gx;
    gemm_glds_body(A.p0, bxx, by, ltid, ls);
  } else if (A.stage == 2){
    rnn_body(A.rnn_in, A.Whh, A.b_hh, A.cat_d, A.dn_out, A.dstt, A.t0r, A.nsr, lg, ltid, ls);
  } else if (A.stage == 4){
    int bxx = lg % A.gx, t = lg / A.gx;
    gemm_glds_body((t >> 3) ? A.p1 : A.p0, bxx, t & 7, ltid, ls);
  }
}

// ---------------- host launcher ----------------
extern "C" void kernel_launch(void* const* d_in, const int* in_sizes, int n_in,
                              void* d_out, int out_size, void* d_ws, size_t ws_size,
                              hipStream_t stream)
{
  const float* ext = (const float*)d_in[0];
  const float* obs = (const float*)d_in[1];
  const float* eps = (const float*)d_in[2];
  const float* Wu  = (const float*)d_in[3];
  const float* bu  = (const float*)d_in[4];
  const float* Wx  = (const float*)d_in[5];
  const float* bx  = (const float*)d_in[6];
  const float* W_ih= (const float*)d_in[7];
  const float* b_ih= (const float*)d_in[8];
  const float* W_hh= (const float*)d_in[9];
  const float* b_hh= (const float*)d_in[10];
  const float* Wa1 = (const float*)d_in[11];
  const float* ba1 = (const float*)d_in[12];
  const float* Wa2 = (const float*)d_in[13];
  const float* ba2 = (const float*)d_in[14];
  const float* pf1W= (const float*)d_in[15]; const float* pf1b = (const float*)d_in[16];
  const float* pf2W= (const float*)d_in[17]; const float* pf2b = (const float*)d_in[18];
  const float* pmuW= (const float*)d_in[19]; const float* pmub = (const float*)d_in[20];
  const float* plsW= (const float*)d_in[21]; const float* plsb = (const float*)d_in[22];
  const float* qf1W= (const float*)d_in[23]; const float* qf1b = (const float*)d_in[24];
  const float* qf2W= (const float*)d_in[25]; const float* qf2b = (const float*)d_in[26];
  const float* qmuW= (const float*)d_in[27]; const float* qmub = (const float*)d_in[28];

  int NC = 0;
  const int cands[5] = {4,8,16,32,64};
  size_t rows = 0;
  for (int ci=0; ci<5; ci++){
    size_t r = (size_t)(LSEQ/cands[ci])*BATCH;
    size_t elems = 2600000 + r*5120;       // fixed + bufA/B/C + 2x(preP+preQ)
    if (elems * 2 <= ws_size){ NC = cands[ci]; rows = r; break; }
  }
  if (!NC) return;
  const int nsteps = LSEQ/NC;
  const int gx = (int)(rows/128);

  unsigned short* ws = (unsigned short*)d_ws;
  size_t off = 0;
  auto alloc = [&](size_t elems){
    unsigned short* p = ws + off;
    off += (elems + 127) & ~(size_t)127;
    return p;
  };

  unsigned short* Wu_t  = alloc(64*256);
  unsigned short* Wx_t  = alloc(64*256);
  unsigned short* Wih_t = alloc(256*256);
  unsigned short* Whh_t = alloc(256*256);
  unsigned short* Wa1_t = alloc(512*256);
  unsigned short* fAp   = alloc(1024*256);
  unsigned short* fAq   = alloc(1024*256);
  unsigned short* GAp   = alloc(1024*256);
  float*          gbp   = (float*)alloc(2048);
  unsigned short* Wzz   = alloc(4*2*256*128);
  unsigned short* W2z   = alloc(4*2*128*256);
  unsigned short* d_state = alloc(256*256);
  unsigned short* z_state = alloc(256*128);
  unsigned short* mbx  = alloc(16*2*4*4096);
  int*   flg  = (int*)alloc(4096);
  unsigned short* bufA  = alloc(rows*256);
  unsigned short* bufB  = alloc(rows*256);
  unsigned short* bufC  = alloc(rows*512);
  unsigned short* preP0 = alloc(rows*1024);
  unsigned short* preP1 = alloc(rows*1024);
  unsigned short* preQ0 = alloc(rows*1024);
  unsigned short* preQ1 = alloc(rows*1024);
  if (off * sizeof(unsigned short) > ws_size) return;

  float* out_mu = (float*)d_out;
  float* out_ls = out_mu + (size_t)LSEQ*BATCH*STATE;
  float* out_dn = out_ls + (size_t)LSEQ*BATCH*STATE;
  float* out_zn = out_dn + (size_t)BATCH*KDIM;

  WDescs wd;
  int wi = 0;
  auto add = [&](const float* s, unsigned short* d, int Kk, int Nn, int ld, int ro, int co){
    wd.d[wi].src = s; wd.d[wi].dst = d; wd.d[wi].K = Kk; wd.d[wi].N = Nn;
    wd.d[wi].ld = ld; wd.d[wi].rowoff = ro; wd.d[wi].coloff = co; wi++;
  };
  add(Wu,   Wu_t,  64, 256, 256, 0, 0);
  add(Wx,   Wx_t,  64, 256, 256, 0, 0);
  add(W_ih, Wih_t, 256, 256, 256, 0, 0);
  add(W_hh, Whh_t, 256, 256, 256, 0, 0);
  add(Wa1,  Wa1_t, 512, 256, 256, 0, 0);
  add(pf1W, fAp,            256, 512, 512, 128, 0);
  add(pf2W, fAp + 512*256,  256, 512, 512, 128, 0);
  add(qf1W, fAq,            256, 512, 512, 128, 0);
  add(qf2W, fAq + 512*256,  256, 512, 512, 128, 0);
  for (int c=0; c<4; c++){
    const float* s1 = (c < 2) ? pf1W : qf1W;
    const float* s2 = (c < 2) ? pf2W : qf2W;
    add(s1, Wzz + (size_t)(c*2+0)*32768, 128, 256, 512, 0, (c&1)*256);
    add(s2, Wzz + (size_t)(c*2+1)*32768, 128, 256, 512, 0, (c&1)*256);
  }
  add(pmuW, W2z + (size_t)(0*2+0)*32768, 256, 128, 128, 0,   0);
  add(plsW, W2z + (size_t)(0*2+1)*32768, 256, 128, 128, 0,   0);
  add(pmuW, W2z + (size_t)(1*2+0)*32768, 256, 128, 128, 256, 0);
  add(plsW, W2z + (size_t)(1*2+1)*32768, 256, 128, 128, 256, 0);
  add(qmuW, W2z + (size_t)(2*2+0)*32768, 256, 128, 128, 0,   0);
  add(qmuW, W2z + (size_t)(3*2+0)*32768, 256, 128, 128, 256, 0);

  convert_weights<<<dim3(512, wi), 256, 0, stream>>>(wd);
  compose_GA<<<1024, 256, 0, stream>>>(Wa2, ba2, fAp, pf1b, pf2b, GAp, gbp);
  init_flags<<<8, 256, 0, stream>>>(flg);

  int s4 = (nsteps/5) & ~1;
  int segs[5] = {s4, s4, s4, s4, nsteps - 4*s4};

  auto zfill = [&](MegaArgs& A, int c_z){
    A.zP = (c_z & 1) ? preP1 : preP0;
    A.zQ = (c_z & 1) ? preQ1 : preQ0;
    A.Wzz = Wzz; A.W2 = W2z; A.pmub = pmub; A.plsb = plsb; A.qmub = qmub;
    A.eps = eps; A.out_mu = out_mu; A.out_ls = out_ls; A.out_zn = out_zn;
    A.zst = z_state; A.mb = mbx; A.flags = flg;
  };

  for (int c=0; c<NC; ++c){
    const size_t row0 = (size_t)c * nsteps * BATCH;
    unsigned short* pP = (c & 1) ? preP1 : preP0;
    unsigned short* pQ = (c & 1) ? preQ1 : preQ0;
    int zo = 0;
    for (int st=0; st<5; st++){
      MegaArgs A{};
      zfill(A, c-1);
      A.t0z = (c-1)*nsteps + zo;
      A.poff = zo;
      A.nsz = (c == 0) ? 0 : segs[st];
      zo += segs[st];
      A.stage = st; A.gx = gx;
      int nphys;
      if (st == 0){
        A.e0 = GArg{ext + row0*64, Wu_t, bu, bu, bufA, 64, 256, 0,   64, 1, 1};
        A.e1 = GArg{obs + row0*64, Wx_t, bx, bx, bufC, 64, 512, 256, 64, 1, 1};
        nphys = gx*2;
      } else if (st == 1){
        A.p0 = GArg2{bufA, Wih_t, b_ih, b_ih, bufB, 256, 256, 0, 256, 0};
        nphys = gx;
      } else if (st == 2){
        A.rnn_in = bufB; A.Whh = Whh_t; A.b_hh = b_hh; A.cat_d = bufC;
        A.dn_out = out_dn; A.dstt = d_state; A.t0r = c*nsteps; A.nsr = nsteps;
        nphys = 8;
      } else if (st == 3){
        A.p0 = GArg2{bufC, Wa1_t, ba1, ba1, bufA, 512, 256, 0, 512, 1};
        nphys = gx;
      } else {
        A.p0 = GArg2{bufA, GAp, gbp, gbp + 512, pP, 256, 1024, 0, 256, 0};
        A.p1 = GArg2{bufC, fAq, qf1b, qf2b, pQ, 512, 1024, 0, 256, 0};
        nphys = gx*8;
      }
      mega<<<64 + nphys, 512, 0, stream>>>(A);
    }
  }
  // drain: zrec of last chunk, no prelude
  {
    MegaArgs A{};
    zfill(A, NC-1);
    A.t0z = (NC-1)*nsteps; A.poff = 0; A.nsz = nsteps;
    A.stage = 5; A.gx = gx;
    mega<<<64, 512, 0, stream>>>(A);
  }
}